// Round 10
// baseline (238.652 us; speedup 1.0000x reference)
//
#include <hip/hip_runtime.h>
#include <hip/hip_bf16.h>

// FactorizedGenerator: per-coordinate MLP 8 -> 64 -> 64 -> 64 -> 1 (SiLU), D=256, B=4096.
// Split-bf16 MFMA emulation of fp32 GEMMs, transposed compute D = W^T @ H^T.
// R8 (2nd resubmit; R8/R9 benches were infra failures): BARRIER-FREE. Each wave owns
//     32 rows x all 64 feats end-to-end; act lives in a private 4KB LDS strip per wave
//     (within-wave DS ordering => no __syncthreads). R7 finding: all pipes <50%,
//     occupancy-insensitive => barrier-burst serialization hypothesis.

#define NDIM 256
#define LDIM 8
#define HDIM 64
#define BDIM 4096
#define BT   128

// per-d weight record layout (bytes) — plain (global reads don't bank-conflict)
#define REC_W1P   0        // [64][24] bf16: ks 0-7 W1hi, 8-15 W1hi, 16-23 W1lo
#define REC_W2H   3072     // [64][64] bf16 W^T (out-feat-major, 16B k-chunks); lo twin +8192
#define REC_W2L   11264
#define REC_W3H   19456
#define REC_W3L   27648
#define REC_COEF  35840    // 256 f32: [0,64) b1, [64,128) b2, [128,192) b3, [192,256) Wo
#define REC_SIZE  36864

#define LDS_SIZE  16384    // 4 waves x [32 rows][64 feats] bf16 (4KB strips), XOR-swizzled

typedef __bf16 bf16x8 __attribute__((ext_vector_type(8)));
typedef __bf16 bf16x4 __attribute__((ext_vector_type(4)));
typedef float  f32x4  __attribute__((ext_vector_type(4)));

__device__ __forceinline__ float silu_f(float x) {
  return x * __builtin_amdgcn_rcpf(1.0f + __expf(-x));
}

// ---------------------------------------------------------------------------
// setup: fp32 weights -> packed bf16 hi/lo records. grid (256, 3). (unchanged)
// ---------------------------------------------------------------------------
__global__ void setup_weights(const float* __restrict__ W1, const float* __restrict__ b1,
                              const float* __restrict__ W2, const float* __restrict__ b2,
                              const float* __restrict__ W3, const float* __restrict__ b3,
                              const float* __restrict__ Wo, char* __restrict__ ws) {
  const int d = blockIdx.x;
  const int y = blockIdx.y;
  const int t = threadIdx.x;
  __shared__ float tile[64 * 65];
  char* rec = ws + (size_t)d * REC_SIZE;

  if (y == 0) {
    for (int idx = t; idx < LDIM * HDIM; idx += 256)
      tile[(idx >> 6) * 65 + (idx & 63)] = W1[d * LDIM * HDIM + idx];   // tile[l][o]
    __syncthreads();
    if (t < 64) {
      __bf16* w1p = (__bf16*)(rec + REC_W1P) + t * 24;
#pragma unroll
      for (int ks = 0; ks < 8; ++ks) {
        float f = tile[ks * 65 + t];
        __bf16 h = (__bf16)f;
        w1p[ks] = h;
        w1p[8 + ks] = h;
        w1p[16 + ks] = (__bf16)(f - (float)h);
      }
    }
    float* coef = (float*)(rec + REC_COEF);
    float v;
    if (t < 64)       v = b1[d * 64 + t];
    else if (t < 128) v = b2[d * 64 + (t - 64)];
    else if (t < 192) v = b3[d * 64 + (t - 128)];
    else              v = Wo[d * 64 + (t - 192)];
    coef[t] = v;
  } else {
    const float* src = (y == 1 ? W2 : W3) + (size_t)d * 4096;
    const int hibase = (y == 1 ? REC_W2H : REC_W3H);
    for (int idx = t; idx < 4096; idx += 256)
      tile[(idx >> 6) * 65 + (idx & 63)] = src[idx];   // tile[kin][o]
    __syncthreads();
    const int o = t >> 2;
    const int q = t & 3;
    bf16x8 h0, h1, l0, l1;
#pragma unroll
    for (int j = 0; j < 8; ++j) {
      float f = tile[(q * 16 + j) * 65 + o];
      __bf16 h = (__bf16)f;
      h0[j] = h; l0[j] = (__bf16)(f - (float)h);
      float g = tile[(q * 16 + 8 + j) * 65 + o];
      __bf16 hg = (__bf16)g;
      h1[j] = hg; l1[j] = (__bf16)(g - (float)hg);
    }
    char* dst = rec + hibase + o * 128 + q * 32;
    *(bf16x8*)(dst)              = h0;
    *(bf16x8*)(dst + 16)         = h1;
    *(bf16x8*)(dst + 8192)       = l0;
    *(bf16x8*)(dst + 8192 + 16)  = l1;
  }
}

// ---------------------------------------------------------------------------
// main: one block = (one d, 128 rows) as 4 INDEPENDENT waves of 32 rows each.
// No __syncthreads anywhere. acc[mt in 4][nt in 2]: feat = mt*16+lg*4+i,
// row = r0 + nt*16 + l15.
// ---------------------------------------------------------------------------
__global__ __launch_bounds__(256, 4)
void mlp_main(const float* __restrict__ z, const char* __restrict__ ws,
              const float* __restrict__ bo, float* __restrict__ out) {
  __shared__ __align__(16) char smem[LDS_SIZE];

  const int bx  = (int)blockIdx.x;
  const int swz = (bx & 7) * 1024 + (bx >> 3);   // 8192 blocks, bijective XCD chunking
  const int d   = swz >> 5;
  const int b0  = (swz & 31) * BT;

  const int t    = (int)threadIdx.x;
  const int lane = t & 63;
  const int wq   = t >> 6;        // wave = row quarter
  const int l15  = lane & 15;
  const int lg   = lane >> 4;
  const int x7   = l15 & 7;
  const int r0   = b0 + wq * 32;

  char* act = smem + wq * 4096;   // private [32][64] bf16, 16B-chunk XOR swizzle

  const char* rec   = ws + (size_t)d * REC_SIZE;
  const float* coef = (const float*)(rec + REC_COEF);

  // ---- z fragments (rows r0 + nt*16 + l15), hi/lo split, select by k-slot parity ----
  bf16x8 zf[2];
#pragma unroll
  for (int nt = 0; nt < 2; ++nt) {
    const int r = r0 + nt * 16 + l15;
    const float* zp = z + ((size_t)r * NDIM + d) * LDIM;
    float4 q0 = *(const float4*)zp;
    float4 q1 = *(const float4*)(zp + 4);
    float f[8] = {q0.x, q0.y, q0.z, q0.w, q1.x, q1.y, q1.z, q1.w};
    bf16x8 hv, lv;
#pragma unroll
    for (int j = 0; j < 8; ++j) {
      __bf16 h = (__bf16)f[j];
      hv[j] = h;
      lv[j] = (__bf16)(f[j] - (float)h);
    }
    zf[nt] = (lg & 1) ? lv : hv;   // lg 0,2 -> hi; 1 -> lo; 3 -> lo (hits zero A-frag)
  }

  f32x4 acc[4][2];

  // ---- layer 1: A = [W1hi | W1hi | W1lo | 0] (global), B = [zhi | zlo | zhi | zlo] ----
  {
    bf16x8 a1[4];
#pragma unroll
    for (int mt = 0; mt < 4; ++mt) {
      if (lg < 3) {
        a1[mt] = *(const bf16x8*)(rec + REC_W1P + (mt * 16 + l15) * 48 + lg * 16);
      } else {
        a1[mt] = (bf16x8)((__bf16)0.0f);
      }
    }
#pragma unroll
    for (int mt = 0; mt < 4; ++mt) {
      f32x4 b = *(const f32x4*)(coef + mt * 16 + lg * 4);   // b1
#pragma unroll
      for (int nt = 0; nt < 2; ++nt) acc[mt][nt] = b;
    }
#pragma unroll
    for (int mt = 0; mt < 4; ++mt)
#pragma unroll
      for (int nt = 0; nt < 2; ++nt)
        acc[mt][nt] = __builtin_amdgcn_mfma_f32_16x16x32_bf16(a1[mt], zf[nt], acc[mt][nt], 0, 0, 0);
  }

  // ---- transition 1: silu -> bf16 -> private LDS strip (swizzled) ----
#pragma unroll
  for (int mt = 0; mt < 4; ++mt) {
    const int cw = ((2 * mt + (lg >> 1)) ^ x7) * 16 + 8 * (lg & 1);
#pragma unroll
    for (int nt = 0; nt < 2; ++nt) {
      const int rl = nt * 16 + l15;
      bf16x4 hv;
#pragma unroll
      for (int i = 0; i < 4; ++i) hv[i] = (__bf16)silu_f(acc[mt][nt][i]);
      *(bf16x4*)(act + rl * 128 + cw) = hv;
    }
  }

  // ---- mid layers 2 & 3: acc = (Wh + Wl) * act_hi ----
#pragma unroll
  for (int L = 0; L < 2; ++L) {
    const char* wh = rec + (L == 0 ? REC_W2H : REC_W3H);
    const float* biasf = coef + (L == 0 ? 64 : 128);
#pragma unroll
    for (int mt = 0; mt < 4; ++mt) {
      f32x4 b = *(const f32x4*)(biasf + mt * 16 + lg * 4);
#pragma unroll
      for (int nt = 0; nt < 2; ++nt) acc[mt][nt] = b;
    }
#pragma unroll
    for (int ks = 0; ks < 2; ++ks) {
      bf16x8 ah[4], al[4], bh[2];
#pragma unroll
      for (int mt = 0; mt < 4; ++mt) {
        const char* p = wh + (mt * 16 + l15) * 128 + ks * 64 + lg * 16;
        ah[mt] = *(const bf16x8*)p;
        al[mt] = *(const bf16x8*)(p + 8192);    // W lo twin
      }
#pragma unroll
      for (int nt = 0; nt < 2; ++nt) {
        const int rl = nt * 16 + l15;
        bh[nt] = *(const bf16x8*)(act + rl * 128 + (((4 * ks + lg) ^ x7) << 4));
      }
#pragma unroll
      for (int mt = 0; mt < 4; ++mt)
#pragma unroll
        for (int nt = 0; nt < 2; ++nt)
          acc[mt][nt] = __builtin_amdgcn_mfma_f32_16x16x32_bf16(ah[mt], bh[nt], acc[mt][nt], 0, 0, 0);
#pragma unroll
      for (int mt = 0; mt < 4; ++mt)
#pragma unroll
        for (int nt = 0; nt < 2; ++nt)
          acc[mt][nt] = __builtin_amdgcn_mfma_f32_16x16x32_bf16(al[mt], bh[nt], acc[mt][nt], 0, 0, 0);
    }

    if (L == 0) {
      // transition 2 (same-wave LDS reuse: DS ops are wave-ordered; no barrier needed)
#pragma unroll
      for (int mt = 0; mt < 4; ++mt) {
        const int cw = ((2 * mt + (lg >> 1)) ^ x7) * 16 + 8 * (lg & 1);
#pragma unroll
        for (int nt = 0; nt < 2; ++nt) {
          const int rl = nt * 16 + l15;
          bf16x4 hv;
#pragma unroll
          for (int i = 0; i < 4; ++i) hv[i] = (__bf16)silu_f(acc[mt][nt][i]);
          *(bf16x4*)(act + rl * 128 + cw) = hv;
        }
      }
    }
  }

  // ---- output: out[r] = sum_f silu(h3[f]) * Wo[f] + bo ----
  f32x4 wof[4];
#pragma unroll
  for (int mt = 0; mt < 4; ++mt)
    wof[mt] = *(const f32x4*)(coef + 192 + mt * 16 + lg * 4);
  const float bov = bo[d];
#pragma unroll
  for (int nt = 0; nt < 2; ++nt) {
    float part = 0.0f;
#pragma unroll
    for (int mt = 0; mt < 4; ++mt)
#pragma unroll
      for (int i = 0; i < 4; ++i)
        part += silu_f(acc[mt][nt][i]) * wof[mt][i];
    part += __shfl_xor(part, 16);
    part += __shfl_xor(part, 32);
    if (lg == 0)
      out[(size_t)(r0 + nt * 16 + l15) * NDIM + d] = part + bov;
  }
}

// ---------------------------------------------------------------------------
extern "C" void kernel_launch(void* const* d_in, const int* in_sizes, int n_in,
                              void* d_out, int out_size, void* d_ws, size_t ws_size,
                              hipStream_t stream) {
  const float* z  = (const float*)d_in[0];
  const float* W1 = (const float*)d_in[1];
  const float* b1 = (const float*)d_in[2];
  const float* W2 = (const float*)d_in[3];
  const float* b2 = (const float*)d_in[4];
  const float* W3 = (const float*)d_in[5];
  const float* b3 = (const float*)d_in[6];
  const float* Wo = (const float*)d_in[7];
  const float* bo = (const float*)d_in[8];
  float* out = (float*)d_out;
  char* ws = (char*)d_ws;

  setup_weights<<<dim3(NDIM, 3), 256, 0, stream>>>(W1, b1, W2, b2, W3, b3, Wo, ws);
  mlp_main<<<NDIM * (BDIM / BT), 256, 0, stream>>>(z, ws, bo, out);
}